// Round 5
// baseline (71.553 us; speedup 1.0000x reference)
//
#include <hip/hip_runtime.h>

typedef float v2f __attribute__((ext_vector_type(2)));

constexpr int IN_DIM = 21;
constexpr int HID = 5;
constexpr int BLK = 256;
constexpr int WAVES = BLK / 64;          // 4
constexpr int EPW = 128;                 // elements per wave (2 per lane)
constexpr int EPB = WAVES * EPW;         // 512
constexpr int XW_F = EPW * IN_DIM;       // 2688 floats (10752 B) x-region per wave
constexpr int HCW_F = 4 * EPW * HID;     // 2560 floats (10240 B) h/c-region per wave
constexpr float LOG2E = 1.44269504088896340736f;

__device__ __forceinline__ v2f splat(float s) { v2f r; r.x = s; r.y = s; return r; }
__device__ __forceinline__ v2f vfma(v2f a, v2f b, v2f c) {
    return __builtin_elementwise_fma(a, b, c);
}
__device__ __forceinline__ v2f vexp2(v2f x) {
    v2f r; r.x = __builtin_amdgcn_exp2f(x.x); r.y = __builtin_amdgcn_exp2f(x.y); return r;
}
__device__ __forceinline__ v2f vrcp(v2f x) {
    v2f r; r.x = __builtin_amdgcn_rcpf(x.x); r.y = __builtin_amdgcn_rcpf(x.y); return r;
}
__device__ __forceinline__ v2f sigmoid2(v2f x) {          // 1/(1+e^-x)
    v2f t = vexp2(x * splat(-LOG2E));
    return vrcp(t + splat(1.0f));
}
__device__ __forceinline__ v2f tanh2(v2f x) {             // 1 - 2/(e^2x+1)
    v2f t = vexp2(x * splat(2.0f * LOG2E));
    v2f r = vrcp(t + splat(1.0f));
    return vfma(splat(-2.0f), r, splat(1.0f));
}
__device__ __forceinline__ float ssig(float x)  { return 1.0f / (1.0f + __expf(-x)); }
__device__ __forceinline__ float stanh(float x) { return 1.0f - 2.0f / (__expf(2.0f * x) + 1.0f); }

// one LSTM layer on packed element-pairs; L = input width
template <int L>
__device__ __forceinline__ void lstm_layer(const v2f* __restrict__ xin,
                                           const v2f* __restrict__ hv,
                                           const v2f* __restrict__ cv,
                                           const float* __restrict__ Wih,
                                           const float* __restrict__ Whh,
                                           const float* __restrict__ bih,
                                           const float* __restrict__ bhh,
                                           v2f* __restrict__ hout) {
#pragma unroll
    for (int k = 0; k < HID; ++k) {
        v2f ai = splat(bih[k]           + bhh[k]);
        v2f af = splat(bih[HID + k]     + bhh[HID + k]);
        v2f ag = splat(bih[2*HID + k]   + bhh[2*HID + k]);
        v2f ao = splat(bih[3*HID + k]   + bhh[3*HID + k]);
#pragma unroll
        for (int j = 0; j < L; ++j) {
            ai = vfma(splat(Wih[(k)*L + j]),         xin[j], ai);
            af = vfma(splat(Wih[(HID + k)*L + j]),   xin[j], af);
            ag = vfma(splat(Wih[(2*HID + k)*L + j]), xin[j], ag);
            ao = vfma(splat(Wih[(3*HID + k)*L + j]), xin[j], ao);
        }
#pragma unroll
        for (int kk = 0; kk < HID; ++kk) {
            ai = vfma(splat(Whh[(k)*HID + kk]),         hv[kk], ai);
            af = vfma(splat(Whh[(HID + k)*HID + kk]),   hv[kk], af);
            ag = vfma(splat(Whh[(2*HID + k)*HID + kk]), hv[kk], ag);
            ao = vfma(splat(Whh[(3*HID + k)*HID + kk]), hv[kk], ao);
        }
        v2f ig = sigmoid2(ai);
        v2f fg = sigmoid2(af);
        v2f gg = tanh2(ag);
        v2f og = sigmoid2(ao);
        v2f cn = vfma(fg, cv[k], ig * gg);
        hout[k] = og * tanh2(cn);
    }
}

__global__ __launch_bounds__(BLK) void lstm2_head_pk(
    const float* __restrict__ x,
    const float* __restrict__ h0,
    const float* __restrict__ c0,
    const float* __restrict__ Wih0,
    const float* __restrict__ Whh0,
    const float* __restrict__ bih0,
    const float* __restrict__ bhh0,
    const float* __restrict__ Wih1,
    const float* __restrict__ Whh1,
    const float* __restrict__ bih1,
    const float* __restrict__ bhh1,
    const float* __restrict__ Wlin,
    const float* __restrict__ blin,
    float* __restrict__ out,
    int B)
{
    __shared__ float xls[WAVES * XW_F];                // 43008 B
    __shared__ float hls[WAVES * HCW_F];               // 40960 B  (separate: no reuse)

    const int wave = threadIdx.x >> 6;
    const int lane = threadIdx.x & 63;
    float* xw = xls + wave * XW_F;                     // per-wave private regions
    float* hw = hls + wave * HCW_F;
    const long long wbase = (long long)blockIdx.x * EPB + (long long)wave * EPW;
    const bool full = (wbase + EPW <= (long long)B);

    if (full) {
        // ---- cooperative coalesced load of x tile (2688 floats) ----
        const float* gx = x + wbase * IN_DIM;
        float4 xr[10]; float2 xr2;
#pragma unroll
        for (int r = 0; r < 10; ++r)
            xr[r] = *(const float4*)(gx + r * 256 + lane * 4);
        xr2 = *(const float2*)(gx + 2560 + lane * 2);

        // ---- cooperative coalesced load of 4 h/c tiles (640 floats each) ----
        const float* g4[4] = { h0 + wbase * HID,
                               c0 + wbase * HID,
                               h0 + (long long)B * HID + wbase * HID,
                               c0 + (long long)B * HID + wbase * HID };
        float4 sa[4], sb[4]; float2 sc[4];
#pragma unroll
        for (int tl = 0; tl < 4; ++tl) {
            sa[tl] = *(const float4*)(g4[tl] + lane * 4);
            sb[tl] = *(const float4*)(g4[tl] + 256 + lane * 4);
            sc[tl] = *(const float2*)(g4[tl] + 512 + lane * 2);
        }

        // ---- LDS writes, linear layout (compiler inserts vmcnt waits) ----
#pragma unroll
        for (int r = 0; r < 10; ++r)
            *(float4*)(xw + r * 256 + lane * 4) = xr[r];
        *(float2*)(xw + 2560 + lane * 2) = xr2;
#pragma unroll
        for (int tl = 0; tl < 4; ++tl) {
            float* dst = hw + tl * 640;
            *(float4*)(dst + lane * 4)       = sa[tl];
            *(float4*)(dst + 256 + lane * 4) = sb[tl];
            *(float2*)(dst + 512 + lane * 2) = sc[tl];
        }
    }

    __syncthreads();   // unconditional: no barrier divergence

    if (full) {
        // ---- x pairs from LDS: ds_read2_b32 {j, j+21} ----
        v2f xv[IN_DIM];
        {
            const float* p = xw + 42 * lane;
#pragma unroll
            for (int j = 0; j < IN_DIM; ++j) {
                v2f t; t.x = p[j]; t.y = p[j + IN_DIM]; xv[j] = t;
            }
        }
        // ---- h/c pairs: ds_read2_b32 {k, k+5} ----
        v2f hv0[HID], cv0[HID], hv1[HID], cv1[HID];
        {
            const float* p0 = hw +    0 + 10 * lane;
            const float* p1 = hw +  640 + 10 * lane;
            const float* p2 = hw + 1280 + 10 * lane;
            const float* p3 = hw + 1920 + 10 * lane;
#pragma unroll
            for (int k = 0; k < HID; ++k) {
                hv0[k].x = p0[k]; hv0[k].y = p0[k + 5];
                cv0[k].x = p1[k]; cv0[k].y = p1[k + 5];
                hv1[k].x = p2[k]; hv1[k].y = p2[k + 5];
                cv1[k].x = p3[k]; cv1[k].y = p3[k + 5];
            }
        }

        v2f h1[HID], h2[HID];
        lstm_layer<IN_DIM>(xv, hv0, cv0, Wih0, Whh0, bih0, bhh0, h1);
        lstm_layer<HID>(h1, hv1, cv1, Wih1, Whh1, bih1, bhh1, h2);

        v2f o = splat(blin[0]);
#pragma unroll
        for (int k = 0; k < HID; ++k) o = vfma(splat(Wlin[k]), h2[k], o);
        v2f r = tanh2(o);

        *(v2f*)(out + wbase + 2 * lane) = r;           // coalesced 8B store
    } else {
        // ---- scalar fallback for partial wave tiles ----
        const long long e0 = wbase + 2 * lane;
#pragma unroll
        for (int u = 0; u < 2; ++u) {
            const long long e = e0 + u;
            if (e >= (long long)B) continue;
            float xi[IN_DIM];
            for (int j = 0; j < IN_DIM; ++j) xi[j] = x[e * IN_DIM + j];
            float hp[HID], cp[HID], g[4 * HID], hh1[HID], hh2[HID];
            for (int k = 0; k < HID; ++k) { hp[k] = h0[e * HID + k]; cp[k] = c0[e * HID + k]; }
            for (int rr = 0; rr < 4 * HID; ++rr) {
                float acc = bih0[rr] + bhh0[rr];
                for (int j = 0; j < IN_DIM; ++j) acc = fmaf(Wih0[rr * IN_DIM + j], xi[j], acc);
                for (int k = 0; k < HID; ++k)    acc = fmaf(Whh0[rr * HID + k], hp[k], acc);
                g[rr] = acc;
            }
            for (int k = 0; k < HID; ++k) {
                float cn = fmaf(ssig(g[HID + k]), cp[k], ssig(g[k]) * stanh(g[2 * HID + k]));
                hh1[k] = ssig(g[3 * HID + k]) * stanh(cn);
            }
            const long long off1 = (long long)B * HID;
            for (int k = 0; k < HID; ++k) { hp[k] = h0[off1 + e * HID + k]; cp[k] = c0[off1 + e * HID + k]; }
            for (int rr = 0; rr < 4 * HID; ++rr) {
                float acc = bih1[rr] + bhh1[rr];
                for (int j = 0; j < HID; ++j) acc = fmaf(Wih1[rr * HID + j], hh1[j], acc);
                for (int k = 0; k < HID; ++k) acc = fmaf(Whh1[rr * HID + k], hp[k], acc);
                g[rr] = acc;
            }
            for (int k = 0; k < HID; ++k) {
                float cn = fmaf(ssig(g[HID + k]), cp[k], ssig(g[k]) * stanh(g[2 * HID + k]));
                hh2[k] = ssig(g[3 * HID + k]) * stanh(cn);
            }
            float o = blin[0];
            for (int k = 0; k < HID; ++k) o = fmaf(Wlin[k], hh2[k], o);
            out[e] = stanh(o);
        }
    }
}

extern "C" void kernel_launch(void* const* d_in, const int* in_sizes, int n_in,
                              void* d_out, int out_size, void* d_ws, size_t ws_size,
                              hipStream_t stream) {
    const float* x    = (const float*)d_in[0];
    const float* h0   = (const float*)d_in[1];
    const float* c0   = (const float*)d_in[2];
    const float* Wih0 = (const float*)d_in[3];
    const float* Whh0 = (const float*)d_in[4];
    const float* bih0 = (const float*)d_in[5];
    const float* bhh0 = (const float*)d_in[6];
    const float* Wih1 = (const float*)d_in[7];
    const float* Whh1 = (const float*)d_in[8];
    const float* bih1 = (const float*)d_in[9];
    const float* bhh1 = (const float*)d_in[10];
    const float* Wlin = (const float*)d_in[11];
    const float* blin = (const float*)d_in[12];
    float* out = (float*)d_out;

    const int B = in_sizes[0] / IN_DIM;
    const int grid = (B + EPB - 1) / EPB;
    lstm2_head_pk<<<grid, BLK, 0, stream>>>(
        x, h0, c0, Wih0, Whh0, bih0, bhh0, Wih1, Whh1, bih1, bhh1,
        Wlin, blin, out, B);
}

// Round 6
// 38.458 us; speedup vs baseline: 1.8606x; 1.8606x over previous
//
#include <hip/hip_runtime.h>

typedef float v2f __attribute__((ext_vector_type(2)));

constexpr int IN_DIM = 21;
constexpr int HID = 5;
constexpr int BLK = 256;
constexpr float LOG2E = 1.44269504088896340736f;

__device__ __forceinline__ v2f splat(float s) { v2f r; r.x = s; r.y = s; return r; }
__device__ __forceinline__ v2f vfma(v2f a, v2f b, v2f c) {
    return __builtin_elementwise_fma(a, b, c);
}
__device__ __forceinline__ v2f vexp2(v2f x) {
    v2f r; r.x = __builtin_amdgcn_exp2f(x.x); r.y = __builtin_amdgcn_exp2f(x.y); return r;
}
__device__ __forceinline__ v2f vrcp(v2f x) {
    v2f r; r.x = __builtin_amdgcn_rcpf(x.x); r.y = __builtin_amdgcn_rcpf(x.y); return r;
}
__device__ __forceinline__ v2f sigmoid2(v2f x) {          // 1/(1+e^-x)
    v2f t = vexp2(x * splat(-LOG2E));
    return vrcp(t + splat(1.0f));
}
__device__ __forceinline__ v2f tanh2(v2f x) {             // 1 - 2/(e^2x+1)
    v2f t = vexp2(x * splat(2.0f * LOG2E));
    v2f r = vrcp(t + splat(1.0f));
    return vfma(splat(-2.0f), r, splat(1.0f));
}
__device__ __forceinline__ float ssig(float x)  { return 1.0f / (1.0f + __expf(-x)); }
__device__ __forceinline__ float stanh(float x) { return 1.0f - 2.0f / (__expf(2.0f * x) + 1.0f); }

// one LSTM layer on packed element-pairs; L = input width
template <int L>
__device__ __forceinline__ void lstm_layer(const v2f* __restrict__ xin,
                                           const v2f* __restrict__ hv,
                                           const v2f* __restrict__ cv,
                                           const float* __restrict__ Wih,
                                           const float* __restrict__ Whh,
                                           const float* __restrict__ bih,
                                           const float* __restrict__ bhh,
                                           v2f* __restrict__ hout) {
#pragma unroll
    for (int k = 0; k < HID; ++k) {
        v2f ai = splat(bih[k]           + bhh[k]);
        v2f af = splat(bih[HID + k]     + bhh[HID + k]);
        v2f ag = splat(bih[2*HID + k]   + bhh[2*HID + k]);
        v2f ao = splat(bih[3*HID + k]   + bhh[3*HID + k]);
#pragma unroll
        for (int j = 0; j < L; ++j) {
            ai = vfma(splat(Wih[(k)*L + j]),         xin[j], ai);
            af = vfma(splat(Wih[(HID + k)*L + j]),   xin[j], af);
            ag = vfma(splat(Wih[(2*HID + k)*L + j]), xin[j], ag);
            ao = vfma(splat(Wih[(3*HID + k)*L + j]), xin[j], ao);
        }
#pragma unroll
        for (int kk = 0; kk < HID; ++kk) {
            ai = vfma(splat(Whh[(k)*HID + kk]),         hv[kk], ai);
            af = vfma(splat(Whh[(HID + k)*HID + kk]),   hv[kk], af);
            ag = vfma(splat(Whh[(2*HID + k)*HID + kk]), hv[kk], ag);
            ao = vfma(splat(Whh[(3*HID + k)*HID + kk]), hv[kk], ao);
        }
        v2f ig = sigmoid2(ai);
        v2f fg = sigmoid2(af);
        v2f gg = tanh2(ag);
        v2f og = sigmoid2(ao);
        v2f cn = vfma(fg, cv[k], ig * gg);
        hout[k] = og * tanh2(cn);
    }
}

__global__ __launch_bounds__(BLK) void lstm2_head_pk(
    const float* __restrict__ x,
    const float* __restrict__ h0,
    const float* __restrict__ c0,
    const float* __restrict__ Wih0,
    const float* __restrict__ Whh0,
    const float* __restrict__ bih0,
    const float* __restrict__ bhh0,
    const float* __restrict__ Wih1,
    const float* __restrict__ Whh1,
    const float* __restrict__ bih1,
    const float* __restrict__ bhh1,
    const float* __restrict__ Wlin,
    const float* __restrict__ blin,
    float* __restrict__ out,
    int B)
{
    const long long e0 = 2LL * ((long long)blockIdx.x * BLK + threadIdx.x);
    if (e0 >= B) return;

    if (e0 + 1 < B) {
        // ======== fast path: full element pair, wide loads ========
        // x pair: 42 contiguous floats = 168 B, 8B-aligned (e0 even)
        const float* gx = x + e0 * IN_DIM;
        float xr[42];
        {
            // 16B alignment of gx varies per thread; use float2 granularity (8B-safe)
#pragma unroll
            for (int r = 0; r < 21; ++r)
                *(v2f*)(xr + 2 * r) = *(const v2f*)(gx + 2 * r);
        }
        v2f xv[IN_DIM];
#pragma unroll
        for (int j = 0; j < IN_DIM; ++j) { xv[j].x = xr[j]; xv[j].y = xr[j + IN_DIM]; }

        // h/c pairs: 10 contiguous floats each tensor, 8B-aligned
        const long long off1 = (long long)B * HID;
        const float* ph0 = h0 + e0 * HID;
        const float* pc0 = c0 + e0 * HID;
        const float* ph1 = h0 + off1 + e0 * HID;
        const float* pc1 = c0 + off1 + e0 * HID;
        float wh0[10], wc0[10], wh1[10], wc1[10];
#pragma unroll
        for (int r = 0; r < 5; ++r) {
            *(v2f*)(wh0 + 2 * r) = *(const v2f*)(ph0 + 2 * r);
            *(v2f*)(wc0 + 2 * r) = *(const v2f*)(pc0 + 2 * r);
            *(v2f*)(wh1 + 2 * r) = *(const v2f*)(ph1 + 2 * r);
            *(v2f*)(wc1 + 2 * r) = *(const v2f*)(pc1 + 2 * r);
        }
        v2f hv0[HID], cv0[HID], hv1[HID], cv1[HID];
#pragma unroll
        for (int k = 0; k < HID; ++k) {
            hv0[k].x = wh0[k]; hv0[k].y = wh0[HID + k];
            cv0[k].x = wc0[k]; cv0[k].y = wc0[HID + k];
            hv1[k].x = wh1[k]; hv1[k].y = wh1[HID + k];
            cv1[k].x = wc1[k]; cv1[k].y = wc1[HID + k];
        }

        v2f h1[HID], h2[HID];
        lstm_layer<IN_DIM>(xv, hv0, cv0, Wih0, Whh0, bih0, bhh0, h1);
        lstm_layer<HID>(h1, hv1, cv1, Wih1, Whh1, bih1, bhh1, h2);

        v2f o = splat(blin[0]);
#pragma unroll
        for (int k = 0; k < HID; ++k) o = vfma(splat(Wlin[k]), h2[k], o);
        v2f r = tanh2(o);
        *(v2f*)(out + e0) = r;                            // 8B store, e0 even
    } else {
        // ======== scalar tail (single trailing element) ========
        const long long e = e0;
        float xi[IN_DIM];
        for (int j = 0; j < IN_DIM; ++j) xi[j] = x[e * IN_DIM + j];
        float hp[HID], cp[HID], g[4 * HID], hh1[HID], hh2[HID];
        for (int k = 0; k < HID; ++k) { hp[k] = h0[e * HID + k]; cp[k] = c0[e * HID + k]; }
        for (int rr = 0; rr < 4 * HID; ++rr) {
            float acc = bih0[rr] + bhh0[rr];
            for (int j = 0; j < IN_DIM; ++j) acc = fmaf(Wih0[rr * IN_DIM + j], xi[j], acc);
            for (int k = 0; k < HID; ++k)    acc = fmaf(Whh0[rr * HID + k], hp[k], acc);
            g[rr] = acc;
        }
        for (int k = 0; k < HID; ++k) {
            float cn = fmaf(ssig(g[HID + k]), cp[k], ssig(g[k]) * stanh(g[2 * HID + k]));
            hh1[k] = ssig(g[3 * HID + k]) * stanh(cn);
        }
        const long long off1 = (long long)B * HID;
        for (int k = 0; k < HID; ++k) { hp[k] = h0[off1 + e * HID + k]; cp[k] = c0[off1 + e * HID + k]; }
        for (int rr = 0; rr < 4 * HID; ++rr) {
            float acc = bih1[rr] + bhh1[rr];
            for (int j = 0; j < HID; ++j) acc = fmaf(Wih1[rr * HID + j], hh1[j], acc);
            for (int k = 0; k < HID; ++k) acc = fmaf(Whh1[rr * HID + k], hp[k], acc);
            g[rr] = acc;
        }
        for (int k = 0; k < HID; ++k) {
            float cn = fmaf(ssig(g[HID + k]), cp[k], ssig(g[k]) * stanh(g[2 * HID + k]));
            hh2[k] = ssig(g[3 * HID + k]) * stanh(cn);
        }
        float o = blin[0];
        for (int k = 0; k < HID; ++k) o = fmaf(Wlin[k], hh2[k], o);
        out[e] = stanh(o);
    }
}

extern "C" void kernel_launch(void* const* d_in, const int* in_sizes, int n_in,
                              void* d_out, int out_size, void* d_ws, size_t ws_size,
                              hipStream_t stream) {
    const float* x    = (const float*)d_in[0];
    const float* h0   = (const float*)d_in[1];
    const float* c0   = (const float*)d_in[2];
    const float* Wih0 = (const float*)d_in[3];
    const float* Whh0 = (const float*)d_in[4];
    const float* bih0 = (const float*)d_in[5];
    const float* bhh0 = (const float*)d_in[6];
    const float* Wih1 = (const float*)d_in[7];
    const float* Whh1 = (const float*)d_in[8];
    const float* bih1 = (const float*)d_in[9];
    const float* bhh1 = (const float*)d_in[10];
    const float* Wlin = (const float*)d_in[11];
    const float* blin = (const float*)d_in[12];
    float* out = (float*)d_out;

    const int B = in_sizes[0] / IN_DIM;
    const int epb = 2 * BLK;
    const int grid = (B + epb - 1) / epb;
    lstm2_head_pk<<<grid, BLK, 0, stream>>>(
        x, h0, c0, Wih0, Whh0, bih0, bhh0, Wih1, Whh1, bih1, bhh1,
        Wlin, blin, out, B);
}